// Round 9
// baseline (226.498 us; speedup 1.0000x reference)
//
#include <hip/hip_runtime.h>

typedef _Float16 half8 __attribute__((ext_vector_type(8)));
typedef float floatx4 __attribute__((ext_vector_type(4)));

#define IMG   3136      // 56*56
#define PIMG  3364      // 58*58
#define XP_ELEMS (32 * 58 * 58 * 128)   // 13,778,944 fp16
#define WQ_ELEMS (9 * 256 * 128)        // 294,912 fp16

#define AS1 __attribute__((address_space(1)))
#define AS3 __attribute__((address_space(3)))

// ---------------- merged pre-pass ----------------
// blocks [0,1856): x NCHW fp32 -> zero-padded NHWC fp16 (unchanged, verified)
// blocks [1856,2000): W -> round(W*128) fp16 in A-DIRECT layout:
//   16B unit U: l=U&63, ni=(U>>6)&3, wf=(U>>8)&3, s=U>>10 (s=K-step 0..35)
//   holds filter k = wf*64 + ni*16 + (l&15), channels c = (s&3)*32 + (l>>4)*8 ..+8
//   of tap rs = s>>2. Lane l of wave wf reads unit (s*16+wf*4+ni)*64 + l ->
//   one contiguous 1KB global_load_dwordx4 per (step,ni): weights go straight
//   to VGPRs, no LDS.
__global__ __launch_bounds__(256) void prep_kernel(const float* __restrict__ x,
                                                   const float* __restrict__ W,
                                                   _Float16* __restrict__ xp,
                                                   _Float16* __restrict__ wq) {
    const int bid = blockIdx.x;
    const int t   = threadIdx.x;
    if (bid >= 1856) {
        // ---- quant part: 144 blocks, 36864 16B-units ----
        int U  = (bid - 1856) * 256 + t;
        int l  = U & 63;
        int ni = (U >> 6) & 3;
        int wf = (U >> 8) & 3;
        int s  = U >> 10;                // 0..35
        int rs = s >> 2, cc = s & 3;
        int k  = wf * 64 + ni * 16 + (l & 15);
        int c0 = cc * 32 + (l >> 4) * 8;
        _Float16* d = wq + (long)U * 8;
        #pragma unroll
        for (int j = 0; j < 8; ++j)
            d[j] = (_Float16)rintf(W[(k * 128 + c0 + j) * 9 + rs] * 128.0f);
        return;
    }
    // ---- pad part (unchanged) ----
    const int hh = bid % 58;
    const int n  = bid / 58;
    _Float16* rowbase = xp + ((long)(n * 58 + hh) * 58) * 128;

    if (hh == 0 || hh == 57) {
        #pragma unroll
        for (int i = 0; i < 4; ++i) {
            int idx = i * 256 + t;
            if (idx < 928) *(half8*)(rowbase + idx * 8) = (half8)(_Float16)0.0f;
        }
        return;
    }

    __shared__ _Float16 tile[128 * 57];
    const int h = hh - 1;

    #pragma unroll
    for (int p = 0; p < 7; ++p) {
        int idx = p * 256 + t;              // 7*256 = 1792
        int c   = idx / 14;
        int w4  = (idx % 14) * 4;
        const float4 v = *(const float4*)(x + ((long)(n * 128 + c) * 56 + h) * 56 + w4);
        _Float16* d = tile + c * 57 + w4;
        d[0] = (_Float16)v.x; d[1] = (_Float16)v.y;
        d[2] = (_Float16)v.z; d[3] = (_Float16)v.w;
    }
    __syncthreads();

    #pragma unroll
    for (int p = 0; p < 4; ++p) {
        int idx = p * 256 + t;
        if (idx < 896) {
            int ww = idx >> 4;
            int c0 = (idx & 15) * 8;
            half8 v;
            #pragma unroll
            for (int j = 0; j < 8; ++j) v[j] = tile[(c0 + j) * 57 + ww];
            *(half8*)(rowbase + (ww + 1) * 128 + c0) = v;
        }
    }
    if (t < 32) {
        int ww = (t >> 4) ? 57 : 0;
        int c0 = (t & 15) * 8;
        *(half8*)(rowbase + ww * 128 + c0) = (half8)(_Float16)0.0f;
    }
}

// ---------------- main: implicit GEMM, M=256, N=100352, K=1152 ----------------
// R9: weights BYPASS LDS. Cycle budget showed every prior schedule was
// LDS-pipe serialized: per K64-tile, MFMA 2483 cyc vs LDS-reads 2304 + stage
// 512 cyc -> barrier-lockstep sum ~5300 = measured 5170/tile, MfmaUtil capped
// ~30% in ALL structures (R0/R3/R4/R7/R8). Fix: A-frags load global->VGPR
// directly (contiguous 1KB dwordx4 per (step,ni), wq pre-arranged; W is
// L1/L2-hot: 16KB/step/CU, wf-pairs share lines). LDS carries ONLY pixels:
// BK=32, 16KB/step, 2 gload_lds calls, R0's verified 4-chunk XOR swizzle.
// LDS reads drop 24->8 b128 per wave per K64. Counted vmcnt(6) gate (4 A-reg
// loads + 2 B-stage in flight), never 0 mid-loop. ff double-buffer is NAMED
// (ffA/ffB, unroll-2) per rule #20.
__global__ __launch_bounds__(512, 2) void conv_mfma_kernel(
    const _Float16* __restrict__ xp, const _Float16* __restrict__ wq,
    const float* __restrict__ b, float* __restrict__ out)
{
    __shared__ __align__(16) _Float16 smem[16384];  // 2 bufs x (B 256x32 f16 = 16 KB) = 32 KB

    const int tid = threadIdx.x;
    const int l   = tid & 63;
    const int wv  = tid >> 6;        // 0..7
    const int wp  = wv & 1;          // pixel half (128 of 256)
    const int wf  = wv >> 1;         // filter quarter (64 of 256)
    int bx  = blockIdx.x;
    bx = (bx & 7) * 49 + (bx >> 3);  // XCD swizzle (392 = 8*49, bijective)

    // ---- B staging bases (R0-proven XOR pair): lane l -> LDS row l>>2, chunk
    // l&3 holding global chunk (l&3)^((l>>3)&3); read undoes with
    // kq = ((l>>4)^((l>>1)&3))*8. Verified 0 bank conflicts R0-R8.
    long pbB[2];
    #pragma unroll
    for (int h = 0; h < 2; ++h) {
        const int pix = bx * 256 + h * 128 + wv * 16 + (l >> 2);
        const int n = pix / IMG, hw = pix % IMG;
        pbB[h] = (long)(n * PIMG + (hw / 56) * 58 + (hw % 56)) * 256
               + ((l & 3) ^ ((l >> 3) & 3)) * 16;
    }
    const int kq = ((l >> 4) ^ ((l >> 1) & 3)) * 8;   // B read-side swizzle (halfs)

    floatx4 acc[8][4] = {};

    // stage one pixel K-step tile (256 pix x 32 ch, 2 global_load_lds calls)
    auto stageB = [&](int s, int pbuf) {
        const int rs = s >> 2;
        const int cc = s & 3;
        const int r  = (rs * 11) >> 5;          // rs/3 for rs in [0,9)
        const int s2 = rs - r * 3;
        const long toff = (long)(r * 58 + s2) * 256 + cc * 64;
        const char* xb = (const char*)xp + toff;
        _Float16* dst = smem + pbuf * 8192 + wv * 512;
        __builtin_amdgcn_global_load_lds((AS1 void*)(xb + pbB[0]), (AS3 void*)dst,          16, 0, 0);
        __builtin_amdgcn_global_load_lds((AS1 void*)(xb + pbB[1]), (AS3 void*)(dst + 4096), 16, 0, 0);
    };
    // load this wave's 4 A-fragments for step s straight into registers
    auto loadA = [&](int s, half8 (&ff)[4]) {
        const char* base = (const char*)wq + (long)(s * 16 + wf * 4) * 1024 + l * 16;
        #pragma unroll
        for (int ni = 0; ni < 4; ++ni)
            ff[ni] = *(const half8*)(base + ni * 1024);
    };

    // one K-step: gate on step s's data, compute 32 MFMA, prefetch s+1
    auto body = [&](int s, half8 (&ffC)[4], half8 (&ffN)[4]) {
        const int pb = s & 1;
        if (s < 35) {
            loadA(s + 1, ffN);
            stageB(s + 1, pb ^ 1);
            asm volatile("s_waitcnt vmcnt(6)" ::: "memory");  // s's 6 retired; s+1's 6 in flight
        } else {
            asm volatile("s_waitcnt vmcnt(0)" ::: "memory");
        }
        asm volatile("s_barrier" ::: "memory");               // step s pixels visible
        const _Float16* Bs = smem + pb * 8192;
        __builtin_amdgcn_s_setprio(1);
        #pragma unroll
        for (int mi = 0; mi < 8; ++mi) {
            const half8 pf = *(const half8*)(Bs + (wp * 128 + mi * 16 + (l & 15)) * 32 + kq);
            #pragma unroll
            for (int ni = 0; ni < 4; ++ni)
                acc[mi][ni] = __builtin_amdgcn_mfma_f32_16x16x32_f16(pf, ffC[ni], acc[mi][ni], 0, 0, 0);
        }
        __builtin_amdgcn_s_setprio(0);
        asm volatile("s_barrier" ::: "memory");               // readers done before s+2 overwrites
    };

    half8 ffA[4], ffB[4];
    loadA(0, ffA);
    stageB(0, 0);
    for (int sp = 0; sp < 18; ++sp) {       // named double-buffer, parity static
        body(2 * sp,     ffA, ffB);
        body(2 * sp + 1, ffB, ffA);
    }

    // epilogue: D rows = pixels -> each lane's 4 acc regs = 4 consecutive pixels
    #pragma unroll
    for (int mi = 0; mi < 8; ++mi) {
        const int pix = bx * 256 + wp * 128 + mi * 16 + (l >> 4) * 4;
        const int n  = pix / IMG;
        const int pr = pix - n * IMG;
        float* orow = out + (long)n * 256 * IMG + pr;
        #pragma unroll
        for (int ni = 0; ni < 4; ++ni) {
            const int filt = wf * 64 + ni * 16 + (l & 15);
            const float bq = rintf(b[filt] * 128.0f);
            float4 v;
            v.x = acc[mi][ni][0] * (1.0f / 128.0f) + bq;
            v.y = acc[mi][ni][1] * (1.0f / 128.0f) + bq;
            v.z = acc[mi][ni][2] * (1.0f / 128.0f) + bq;
            v.w = acc[mi][ni][3] * (1.0f / 128.0f) + bq;
            *(float4*)(orow + (long)filt * IMG) = v;
        }
    }
}

// ---------------- fallback (ws too small): direct conv, correct but slow ----------------
__global__ void conv_fallback_kernel(const float* __restrict__ x, const float* __restrict__ W,
                                     const float* __restrict__ b, float* __restrict__ out)
{
    __shared__ float wsm[1152];
    const int k = blockIdx.y;
    for (int i = threadIdx.x; i < 1152; i += 256)
        wsm[i] = rintf(W[k * 1152 + i] * 128.0f);
    __syncthreads();
    const int pix = blockIdx.x * 256 + threadIdx.x;
    const int n = pix / IMG, hw = pix % IMG;
    const int h = hw / 56, w = hw % 56;
    float acc = 0.0f;
    for (int c = 0; c < 128; ++c) {
        const float* xr = x + ((n * 128 + c) * 56) * 56;
        const float* wr = wsm + c * 9;
        #pragma unroll
        for (int r = 0; r < 3; ++r) {
            const int hh = h + r - 1;
            if ((unsigned)hh >= 56u) continue;
            #pragma unroll
            for (int s = 0; s < 3; ++s) {
                const int ww = w + s - 1;
                if ((unsigned)ww >= 56u) continue;
                acc += xr[hh * 56 + ww] * wr[r * 3 + s];
            }
        }
    }
    out[((long)n * 256 + k) * IMG + hw] = acc * (1.0f / 128.0f) + rintf(b[k] * 128.0f);
}

extern "C" void kernel_launch(void* const* d_in, const int* in_sizes, int n_in,
                              void* d_out, int out_size, void* d_ws, size_t ws_size,
                              hipStream_t stream) {
    const float* x = (const float*)d_in[0];
    const float* W = (const float*)d_in[1];
    const float* b = (const float*)d_in[2];
    float* out = (float*)d_out;

    const size_t need = (size_t)XP_ELEMS * 2 + (size_t)WQ_ELEMS * 2;   // 28,147,712 B
    if (ws_size >= need) {
        _Float16* xp = (_Float16*)d_ws;
        _Float16* wq = xp + XP_ELEMS;
        prep_kernel<<<2000, 256, 0, stream>>>(x, W, xp, wq);
        conv_mfma_kernel<<<dim3(392), 512, 0, stream>>>(xp, wq, b, out);
    } else {
        conv_fallback_kernel<<<dim3(392, 256), 256, 0, stream>>>(x, W, b, out);
    }
}

// Round 10
// 213.558 us; speedup vs baseline: 1.0606x; 1.0606x over previous
//
#include <hip/hip_runtime.h>

typedef _Float16 half8 __attribute__((ext_vector_type(8)));
typedef float floatx4 __attribute__((ext_vector_type(4)));

#define IMG   3136      // 56*56
#define PIMG  3364      // 58*58
#define XP_ELEMS (32 * 58 * 58 * 128)   // 13,778,944 fp16
#define WQ_ELEMS (9 * 256 * 128)        // 294,912 fp16

#define AS1 __attribute__((address_space(1)))
#define AS3 __attribute__((address_space(3)))

// ---------------- merged pre-pass ----------------
// blocks [0,1856): x NCHW fp32 -> zero-padded NHWC fp16 (unchanged, verified)
// blocks [1856,2000): W -> round(W*128) fp16, LINEAR [rs][k][c] layout
// (the staging XOR pair lives in the conv kernel's src-offset/read-offset,
//  R0/R3-proven; wq itself stays linear)
__global__ __launch_bounds__(256) void prep_kernel(const float* __restrict__ x,
                                                   const float* __restrict__ W,
                                                   _Float16* __restrict__ xp,
                                                   _Float16* __restrict__ wq) {
    const int bid = blockIdx.x;
    const int t   = threadIdx.x;
    if (bid >= 1856) {
        // ---- quant: 144 blocks x 256 thr x 8 elems = 294912 ----
        const long base = ((long)(bid - 1856) * 256 + t) * 8;
        #pragma unroll
        for (int j = 0; j < 8; ++j) {
            const long idx = base + j;
            const int c  = idx & 127;
            const int k  = (idx >> 7) & 255;
            const int rs = idx >> 15;
            wq[idx] = (_Float16)rintf(W[(k * 128 + c) * 9 + rs] * 128.0f);
        }
        return;
    }
    // ---- pad part (unchanged) ----
    const int hh = bid % 58;
    const int n  = bid / 58;
    _Float16* rowbase = xp + ((long)(n * 58 + hh) * 58) * 128;

    if (hh == 0 || hh == 57) {
        #pragma unroll
        for (int i = 0; i < 4; ++i) {
            int idx = i * 256 + t;
            if (idx < 928) *(half8*)(rowbase + idx * 8) = (half8)(_Float16)0.0f;
        }
        return;
    }

    __shared__ _Float16 tile[128 * 57];
    const int h = hh - 1;

    #pragma unroll
    for (int p = 0; p < 7; ++p) {
        int idx = p * 256 + t;              // 7*256 = 1792
        int c   = idx / 14;
        int w4  = (idx % 14) * 4;
        const float4 v = *(const float4*)(x + ((long)(n * 128 + c) * 56 + h) * 56 + w4);
        _Float16* d = tile + c * 57 + w4;
        d[0] = (_Float16)v.x; d[1] = (_Float16)v.y;
        d[2] = (_Float16)v.z; d[3] = (_Float16)v.w;
    }
    __syncthreads();

    #pragma unroll
    for (int p = 0; p < 4; ++p) {
        int idx = p * 256 + t;
        if (idx < 896) {
            int ww = idx >> 4;
            int c0 = (idx & 15) * 8;
            half8 v;
            #pragma unroll
            for (int j = 0; j < 8; ++j) v[j] = tile[(c0 + j) * 57 + ww];
            *(half8*)(rowbase + (ww + 1) * 128 + c0) = v;
        }
    }
    if (t < 32) {
        int ww = (t >> 4) ? 57 : 0;
        int c0 = (t & 15) * 8;
        *(half8*)(rowbase + ww * 128 + c0) = (half8)(_Float16)0.0f;
    }
}

// ---------------- main: implicit GEMM, M=256, N=100352, K=1152 ----------------
// R10: attack the two NEVER-VARIED invariants behind the flat ~30% MfmaUtil
// (R0/R3/R4/R7/R8 all schedules/geometries identical within noise):
// 1. PIPELINE DEPTH 1 -> now DEPTH 2: triple-buffered LDS, step s issues
//    s+2's 6 global_load_lds, gates vmcnt(12) (= 2 steps in flight), so every
//    load has ~2 full steps (>2x HBM latency) of cover. Never 0 until tail.
// 2. GRID TAIL: 392 blocks/1-resident = guaranteed >=23% makespan loss.
//    Now BN=128 -> 784 blocks (=8x98, bijective XCD swizzle), 72 KB LDS ->
//    2 blocks/CU co-resident (m114 cross-block overlap at barriers/gates).
// 4 waves, wave tile 128 filt x 64 pix (proven). Staging/swizzle pair lifted
// verbatim from R3 (passed, 0 bank conflicts); float4 pixel-row epilogue from
// R8 (passed).
__global__ __launch_bounds__(256, 2) void conv_mfma_kernel(
    const _Float16* __restrict__ xp, const _Float16* __restrict__ wq,
    const float* __restrict__ b, float* __restrict__ out)
{
    __shared__ __align__(16) _Float16 smem[36864];  // 3 bufs x (A 256x32 + B 128x32) = 72 KB

    const int tid = threadIdx.x;
    const int l   = tid & 63;
    const int wv  = tid >> 6;        // 0..3
    const int wm  = wv & 1;          // filter half (128 of 256)
    const int wn  = wv >> 1;         // pixel half (64 of 128)
    int bx  = blockIdx.x;
    bx = (bx & 7) * 98 + (bx >> 3);  // XCD swizzle (784 = 8*98, bijective)

    // R3-proven staging XOR pair: lane l stages LDS chunk l&3 from global
    // chunk (l&3)^((l>>3)&3); reader undoes with kq = ((l>>4)^((l>>1)&3))*8.
    const int lrow = l >> 2;
    const int lch  = ((l & 3) ^ ((l >> 3) & 3)) * 8;
    const int kq   = ((l >> 4) ^ ((l >> 1) & 3)) * 8;

    // A staging offsets: 4 calls cover 256 filter-rows x 32 ch
    int aoff[4];
    #pragma unroll
    for (int i = 0; i < 4; ++i)
        aoff[i] = (i * 64 + wv * 16 + lrow) * 128 + lch;
    // B staging bases: 2 calls cover 128 pixel-rows x 32 ch
    long pbB[2];
    #pragma unroll
    for (int j = 0; j < 2; ++j) {
        const int pix = bx * 128 + j * 64 + wv * 16 + lrow;
        const int n = pix / IMG, hw = pix % IMG;
        pbB[j] = (long)(n * PIMG + (hw / 56) * 58 + (hw % 56)) * 128 + lch;
    }
    const int stA = wv * 512;        // per-wave staging region (halfs)

    floatx4 acc[4][8] = {};          // [pixel frag][filter frag]

    // issue the 6 global_load_lds for K-step s into buffer buf
    auto stage = [&](int s, int buf) {
        const int rs = s >> 2;
        const int cc = s & 3;
        const int r  = (rs * 11) >> 5;          // rs/3 for rs in [0,9)
        const int s2 = rs - r * 3;
        const _Float16* wg = wq + rs * (256 * 128) + cc * 32;
        const _Float16* xg = xp + (r * 58 + s2) * 128 + cc * 32;
        _Float16* A = smem + buf * 12288 + stA;
        _Float16* B = smem + buf * 12288 + 8192 + stA;
        #pragma unroll
        for (int i = 0; i < 4; ++i)
            __builtin_amdgcn_global_load_lds((AS1 void*)(wg + aoff[i]),
                                             (AS3 void*)(A + i * 2048), 16, 0, 0);
        #pragma unroll
        for (int j = 0; j < 2; ++j)
            __builtin_amdgcn_global_load_lds((AS1 void*)(xg + pbB[j]),
                                             (AS3 void*)(B + j * 2048), 16, 0, 0);
    };

    const int frow = wm * 128 + (l & 15);   // filter fragment row base
    const int prow = wn * 64  + (l & 15);   // pixel fragment row base

    // prologue: depth-2 -> steps 0,1 in flight (12 outstanding per wave)
    stage(0, 0);
    stage(1, 1);

    #pragma unroll 3
    for (int s = 0; s < 36; ++s) {
        const int buf = s % 3;
        // issue s+2 into the buffer freed by step s-1 (trailing barrier of
        // s-1 = WAR fence), then counted gate: drain step s's 6 only.
        if (s < 34) {
            stage(s + 2, (s + 2) % 3);
            asm volatile("s_waitcnt vmcnt(12)" ::: "memory");
        } else if (s == 34) {
            asm volatile("s_waitcnt vmcnt(6)" ::: "memory");
        } else {
            asm volatile("s_waitcnt vmcnt(0)" ::: "memory");
        }
        asm volatile("s_barrier" ::: "memory");   // step s data visible to all

        const _Float16* As = smem + buf * 12288;
        const _Float16* Bs = As + 8192;
        half8 pf[4], ff[8];
        #pragma unroll
        for (int mi = 0; mi < 4; ++mi)
            pf[mi] = *(const half8*)(Bs + (prow + mi * 16) * 32 + kq);
        #pragma unroll
        for (int ni = 0; ni < 8; ++ni)
            ff[ni] = *(const half8*)(As + (frow + ni * 16) * 32 + kq);

        __builtin_amdgcn_s_setprio(1);
        #pragma unroll
        for (int mi = 0; mi < 4; ++mi)
            #pragma unroll
            for (int ni = 0; ni < 8; ++ni)
                acc[mi][ni] = __builtin_amdgcn_mfma_f32_16x16x32_f16(pf[mi], ff[ni], acc[mi][ni], 0, 0, 0);
        __builtin_amdgcn_s_setprio(0);

        asm volatile("s_barrier" ::: "memory");   // reads done: buf may be overwritten
    }

    // epilogue: D rows = pixels -> each lane's 4 acc regs = 4 consecutive pixels
    #pragma unroll
    for (int mi = 0; mi < 4; ++mi) {
        const int pix = bx * 128 + wn * 64 + mi * 16 + (l >> 4) * 4;
        const int n  = pix / IMG;
        const int pr = pix - n * IMG;
        float* orow = out + (long)n * 256 * IMG + pr;
        #pragma unroll
        for (int ni = 0; ni < 8; ++ni) {
            const int filt = wm * 128 + ni * 16 + (l & 15);
            const float bq = rintf(b[filt] * 128.0f);
            float4 v;
            v.x = acc[mi][ni][0] * (1.0f / 128.0f) + bq;
            v.y = acc[mi][ni][1] * (1.0f / 128.0f) + bq;
            v.z = acc[mi][ni][2] * (1.0f / 128.0f) + bq;
            v.w = acc[mi][ni][3] * (1.0f / 128.0f) + bq;
            *(float4*)(orow + (long)filt * IMG) = v;
        }
    }
}

// ---------------- fallback (ws too small): direct conv, correct but slow ----------------
__global__ void conv_fallback_kernel(const float* __restrict__ x, const float* __restrict__ W,
                                     const float* __restrict__ b, float* __restrict__ out)
{
    __shared__ float wsm[1152];
    const int k = blockIdx.y;
    for (int i = threadIdx.x; i < 1152; i += 256)
        wsm[i] = rintf(W[k * 1152 + i] * 128.0f);
    __syncthreads();
    const int pix = blockIdx.x * 256 + threadIdx.x;
    const int n = pix / IMG, hw = pix % IMG;
    const int h = hw / 56, w = hw % 56;
    float acc = 0.0f;
    for (int c = 0; c < 128; ++c) {
        const float* xr = x + ((n * 128 + c) * 56) * 56;
        const float* wr = wsm + c * 9;
        #pragma unroll
        for (int r = 0; r < 3; ++r) {
            const int hh = h + r - 1;
            if ((unsigned)hh >= 56u) continue;
            #pragma unroll
            for (int s = 0; s < 3; ++s) {
                const int ww = w + s - 1;
                if ((unsigned)ww >= 56u) continue;
                acc += xr[hh * 56 + ww] * wr[r * 3 + s];
            }
        }
    }
    out[((long)n * 256 + k) * IMG + hw] = acc * (1.0f / 128.0f) + rintf(b[k] * 128.0f);
}

extern "C" void kernel_launch(void* const* d_in, const int* in_sizes, int n_in,
                              void* d_out, int out_size, void* d_ws, size_t ws_size,
                              hipStream_t stream) {
    const float* x = (const float*)d_in[0];
    const float* W = (const float*)d_in[1];
    const float* b = (const float*)d_in[2];
    float* out = (float*)d_out;

    const size_t need = (size_t)XP_ELEMS * 2 + (size_t)WQ_ELEMS * 2;   // 28,147,712 B
    if (ws_size >= need) {
        _Float16* xp = (_Float16*)d_ws;
        _Float16* wq = xp + XP_ELEMS;
        prep_kernel<<<2000, 256, 0, stream>>>(x, W, xp, wq);
        conv_mfma_kernel<<<dim3(784), 256, 0, stream>>>(xp, wq, b, out);
    } else {
        conv_fallback_kernel<<<dim3(392, 256), 256, 0, stream>>>(x, W, b, out);
    }
}